// Round 8
// baseline (336.683 us; speedup 1.0000x reference)
//
#include <hip/hip_runtime.h>
#include <hip/hip_bf16.h>

typedef __attribute__((ext_vector_type(8))) short bf16x8;
typedef __attribute__((ext_vector_type(4))) float f32x4;
typedef __attribute__((ext_vector_type(16))) float f32x16;

__device__ __forceinline__ unsigned short f2bf(float x) {
  union { float f; unsigned u; } v; v.f = x;
  unsigned r = v.u + 0x7fffu + ((v.u >> 16) & 1u);
  return (unsigned short)(r >> 16);
}

__device__ __forceinline__ unsigned cvtpk_bf16(float lo, float hi) {
  unsigned r;
  asm("v_cvt_pk_bf16_f32 %0, %1, %2" : "=v"(r) : "v"(lo), "v"(hi));
  return r;
}
__device__ __forceinline__ void pl32swap(unsigned &a, unsigned &b) {
  asm volatile("v_permlane32_swap_b32 %0, %1" : "+v"(a), "+v"(b));
}
__device__ __forceinline__ void gload_lds16(const void* g, void* l) {
  __builtin_amdgcn_global_load_lds((const __attribute__((address_space(1))) void*)g,
                                   (__attribute__((address_space(3))) void*)l, 16, 0, 0);
}

#define SWZ(x) ((x) ^ ((((x) >> 7) & 7) << 4))

// ---------------------------------------------------------------------------
// Weight fp32 -> bf16 pre-convert (Wq scaled by s0).
// ---------------------------------------------------------------------------
__global__ __launch_bounds__(256) void cvt_w(
    const float* __restrict__ W0, const float* __restrict__ W1,
    const float* __restrict__ W2, const float* __restrict__ W3,
    unsigned short* __restrict__ o0, unsigned short* __restrict__ o1,
    unsigned short* __restrict__ o2, unsigned short* __restrict__ o3,
    float s0) {
  const int z = blockIdx.y;
  const float* W = (z == 0) ? W0 : (z == 1) ? W1 : (z == 2) ? W2 : W3;
  unsigned short* o = (z == 0) ? o0 : (z == 1) ? o1 : (z == 2) ? o2 : o3;
  const float s = (z == 0) ? s0 : 1.0f;
  const int i = blockIdx.x * 256 + threadIdx.x;
  const float4 x = ((const float4*)W)[i];
  uint2 u;
  u.x = cvtpk_bf16(x.x * s, x.y * s);
  u.y = cvtpk_bf16(x.z * s, x.w * s);
  ((uint2*)o)[i] = u;
}

// ===========================================================================
// "W-in-LDS, X-streamed" GEMM structure (C^T orientation):
//   D = mfma(A = W rows [n] from swizzled LDS tile, B = X rows [m] loaded
//   directly to registers). Only the 8KB W tile flows through LDS (gload_lds,
//   3-deep ring, counted vmcnt). C/D frag: col = m (lane&15), row = n.
// LDS tile layout per 8KB buffer ([128 n][32 k] bf16): pair p=r>>1, chunk c,
//   gc=((r&1)*4+c)^(p&7), addr p*128+gc*16 -- conflict-free (R6: 0 conflicts).
// vmcnt schedule: step t issues [X(t+1) (order-pinned first), W(t+2)];
//   top-of-step waits vmcnt(2) (leaves W(t+1) in flight), vmcnt(0) on last.
// ===========================================================================

// ---------------------------------------------------------------------------
// Merged Q/K/V projection GEMM. z: 0=Q (Wq pre-scaled), 1=K, 2=V(transposed).
// X fp32 -> register frags via cvt_pk.
// ---------------------------------------------------------------------------
__global__ __launch_bounds__(256) void proj_gemm3(
    const float* __restrict__ A0, const float* __restrict__ A1, const float* __restrict__ A2,
    const unsigned short* __restrict__ W0b, const unsigned short* __restrict__ W1b,
    const unsigned short* __restrict__ W2b,
    const float* __restrict__ b0, const float* __restrict__ b1, const float* __restrict__ b2,
    unsigned short* __restrict__ o0, unsigned short* __restrict__ o1,
    unsigned short* __restrict__ o2) {
  const int K = 1024;
  const int NK = 32;
  __shared__ __align__(16) unsigned short Ws[3][4096];
  const int z = blockIdx.z;
  const float* X = (z == 0) ? A0 : (z == 1) ? A1 : A2;
  const unsigned short* Wb = (z == 0) ? W0b : (z == 1) ? W1b : W2b;
  const float* bias = (z == 0) ? b0 : (z == 1) ? b1 : b2;
  unsigned short* out = (z == 0) ? o0 : (z == 1) ? o1 : o2;
  const float bscale = (z == 0) ? 0.125f * 1.4426950408889634f : 1.0f;
  const int vtrans = (z == 2);

  const int tid = threadIdx.x;
  const int m0 = blockIdx.x * 128;   // X rows
  const int n0 = blockIdx.y * 128;   // W rows
  const int lane = tid & 63;
  const int w = tid >> 6;
  const int wnA = (w >> 1) * 64;     // wave's n-range (A operand)
  const int wmB = (w & 1) * 64;      // wave's m-range (B operand)
  const int fr = lane & 15;
  const int g = lane >> 4;
  const int frh = fr >> 1;
  const int gcf = ((fr & 1) * 4 + g) ^ frh;
  const int aoff = wnA * 64 + frh * 128 + gcf * 16;  // W-frag byte off, +i*1024

  // W gload sources (inverse-swizzled global, linear LDS dest)
  const unsigned short* wsrc[2];
  int wldo[2];
#pragma unroll
  for (int j = 0; j < 2; ++j) {
    const int L = (w * 2 + j) * 64 + lane;
    const int pp = L >> 3, gc = L & 7;
    const int e = gc ^ (pp & 7);
    const int r = pp * 2 + (e >> 2), c = e & 3;
    wsrc[j] = Wb + (size_t)(n0 + r) * K + c * 8;
    wldo[j] = (w * 2 + j) * 1024;
  }

  // X sources: frag j -> row m0+wmB+j*16+fr, cols g*8..+8 (fp32)
  const float* xsrc[4];
#pragma unroll
  for (int j = 0; j < 4; ++j)
    xsrc[j] = X + (size_t)(m0 + wmB + j * 16 + fr) * K + g * 8;

  f32x4 acc[4][4] = {};
  float4 laA[8], laB[8];  // [j*2+half]

#define LOADX(kt, LA)                                                 \
  {                                                                   \
    _Pragma("unroll")                                                 \
    for (int j = 0; j < 4; ++j) {                                     \
      LA[j * 2 + 0] = *(const float4*)(xsrc[j] + (kt) * 32);          \
      LA[j * 2 + 1] = *(const float4*)(xsrc[j] + (kt) * 32 + 4);      \
    }                                                                 \
  }
#define STAGEW(buf, kt)                                               \
  {                                                                   \
    gload_lds16(wsrc[0] + (kt) * 32, (char*)Ws[buf] + wldo[0]);       \
    gload_lds16(wsrc[1] + (kt) * 32, (char*)Ws[buf] + wldo[1]);       \
  }
#define COMPUTE(cb, LA)                                               \
  {                                                                   \
    union { unsigned u[4]; bf16x8 v; } xf[4];                         \
    _Pragma("unroll")                                                 \
    for (int j = 0; j < 4; ++j) {                                     \
      xf[j].u[0] = cvtpk_bf16(LA[j * 2 + 0].x, LA[j * 2 + 0].y);      \
      xf[j].u[1] = cvtpk_bf16(LA[j * 2 + 0].z, LA[j * 2 + 0].w);      \
      xf[j].u[2] = cvtpk_bf16(LA[j * 2 + 1].x, LA[j * 2 + 1].y);      \
      xf[j].u[3] = cvtpk_bf16(LA[j * 2 + 1].z, LA[j * 2 + 1].w);      \
    }                                                                 \
    const char* Ab_ = (const char*)Ws[cb];                            \
    bf16x8 af[4];                                                     \
    _Pragma("unroll")                                                 \
    for (int i = 0; i < 4; ++i) af[i] = *(const bf16x8*)(Ab_ + aoff + i * 1024); \
    _Pragma("unroll")                                                 \
    for (int i = 0; i < 4; ++i)                                       \
      _Pragma("unroll")                                               \
      for (int j = 0; j < 4; ++j)                                     \
        acc[i][j] = __builtin_amdgcn_mfma_f32_16x16x32_bf16(af[i], xf[j].v, acc[i][j], 0, 0, 0); \
  }

  // prologue: X0 (issued first), then W0, W1
  LOADX(0, laA);
  __builtin_amdgcn_sched_barrier(0);
  STAGEW(0, 0); STAGEW(1, 1);
  __builtin_amdgcn_sched_barrier(0);

  int cur = 0;
  for (int kt = 0; kt < NK; kt += 2) {
    // even sub-step: consume laA/X(kt)
    asm volatile("s_waitcnt vmcnt(2)" ::: "memory");
    __builtin_amdgcn_sched_barrier(0);
    __builtin_amdgcn_s_barrier();
    __builtin_amdgcn_sched_barrier(0);
    {
      const int nx1 = (cur == 2) ? 0 : cur + 1;
      const int nx2 = (nx1 == 2) ? 0 : nx1 + 1;
      if (kt + 1 < NK) LOADX(kt + 1, laB);
      __builtin_amdgcn_sched_barrier(0);
      if (kt + 2 < NK) STAGEW(nx2, kt + 2);
      __builtin_amdgcn_sched_barrier(0);
      COMPUTE(cur, laA);
      cur = nx1;
    }
    // odd sub-step: consume laB/X(kt+1)
    if (kt + 1 == NK - 1) asm volatile("s_waitcnt vmcnt(0)" ::: "memory");
    else                  asm volatile("s_waitcnt vmcnt(2)" ::: "memory");
    __builtin_amdgcn_sched_barrier(0);
    __builtin_amdgcn_s_barrier();
    __builtin_amdgcn_sched_barrier(0);
    {
      const int nx1 = (cur == 2) ? 0 : cur + 1;
      const int nx2 = (nx1 == 2) ? 0 : nx1 + 1;
      if (kt + 2 < NK) LOADX(kt + 2, laA);
      __builtin_amdgcn_sched_barrier(0);
      if (kt + 3 < NK) STAGEW(nx2, kt + 3);
      __builtin_amdgcn_sched_barrier(0);
      COMPUTE(cur, laB);
      cur = nx1;
    }
  }
#undef LOADX
#undef STAGEW
#undef COMPUTE

  // epilogue: acc[i][j][r]: n = n0+wnA+i*16+g*4+r, m = m0+wmB+j*16+fr
#pragma unroll
  for (int i = 0; i < 4; ++i) {
    const int nb = n0 + wnA + i * 16 + g * 4;
    const float4 b4 = *(const float4*)&bias[nb];
    const int h = nb >> 6, d0 = nb & 63;
#pragma unroll
    for (int j = 0; j < 4; ++j) {
      const int m = m0 + wmB + j * 16 + fr;
      const int b = m >> 11, t = m & 2047;
      const float v0 = acc[i][j][0] + b4.x * bscale;
      const float v1 = acc[i][j][1] + b4.y * bscale;
      const float v2 = acc[i][j][2] + b4.z * bscale;
      const float v3 = acc[i][j][3] + b4.w * bscale;
      if (vtrans) {
        unsigned short* op = &out[(((size_t)b * 16 + h) * 64 + d0) * 2048 + t];
        op[0] = f2bf(v0); op[2048] = f2bf(v1);
        op[4096] = f2bf(v2); op[6144] = f2bf(v3);
      } else {
        uint2 u;
        u.x = cvtpk_bf16(v0, v1);
        u.y = cvtpk_bf16(v2, v3);
        *(uint2*)(&out[(((size_t)b * 16 + h) * 2048 + t) * 64 + d0]) = u;
      }
    }
  }
}

// ---------------------------------------------------------------------------
// Output projection: D^T = mfma(A=Wo rows from LDS, B=O rows from global).
// O is bf16 -> no cvt at all. fp32 float4 stores.
// ---------------------------------------------------------------------------
__global__ __launch_bounds__(256) void out_gemm(
    const unsigned short* __restrict__ O, const unsigned short* __restrict__ Wb,
    const float* __restrict__ bias, float* __restrict__ out) {
  const int K = 1024;
  const int NK = 32;
  __shared__ __align__(16) unsigned short Ws[3][4096];
  const int tid = threadIdx.x;
  const int m0 = blockIdx.x * 128;
  const int n0 = blockIdx.y * 128;
  const int lane = tid & 63;
  const int w = tid >> 6;
  const int wnA = (w >> 1) * 64;
  const int wmB = (w & 1) * 64;
  const int fr = lane & 15;
  const int g = lane >> 4;
  const int frh = fr >> 1;
  const int gcf = ((fr & 1) * 4 + g) ^ frh;
  const int aoff = wnA * 64 + frh * 128 + gcf * 16;

  const unsigned short* wsrc[2];
  int wldo[2];
#pragma unroll
  for (int j = 0; j < 2; ++j) {
    const int L = (w * 2 + j) * 64 + lane;
    const int pp = L >> 3, gc = L & 7;
    const int e = gc ^ (pp & 7);
    const int r = pp * 2 + (e >> 2), c = e & 3;
    wsrc[j] = Wb + (size_t)(n0 + r) * K + c * 8;
    wldo[j] = (w * 2 + j) * 1024;
  }

  const unsigned short* xsrc[4];
#pragma unroll
  for (int j = 0; j < 4; ++j)
    xsrc[j] = O + (size_t)(m0 + wmB + j * 16 + fr) * K + g * 8;

  f32x4 acc[4][4] = {};
  uint4 laA[4], laB[4];

#define LOADX(kt, LA)                                                 \
  {                                                                   \
    _Pragma("unroll")                                                 \
    for (int j = 0; j < 4; ++j)                                       \
      LA[j] = *(const uint4*)(xsrc[j] + (kt) * 32);                   \
  }
#define STAGEW(buf, kt)                                               \
  {                                                                   \
    gload_lds16(wsrc[0] + (kt) * 32, (char*)Ws[buf] + wldo[0]);       \
    gload_lds16(wsrc[1] + (kt) * 32, (char*)Ws[buf] + wldo[1]);       \
  }
#define COMPUTE(cb, LA)                                               \
  {                                                                   \
    const char* Ab_ = (const char*)Ws[cb];                            \
    bf16x8 af[4];                                                     \
    _Pragma("unroll")                                                 \
    for (int i = 0; i < 4; ++i) af[i] = *(const bf16x8*)(Ab_ + aoff + i * 1024); \
    _Pragma("unroll")                                                 \
    for (int i = 0; i < 4; ++i)                                       \
      _Pragma("unroll")                                               \
      for (int j = 0; j < 4; ++j)                                     \
        acc[i][j] = __builtin_amdgcn_mfma_f32_16x16x32_bf16(af[i], *(const bf16x8*)&LA[j], acc[i][j], 0, 0, 0); \
  }

  LOADX(0, laA);
  __builtin_amdgcn_sched_barrier(0);
  STAGEW(0, 0); STAGEW(1, 1);
  __builtin_amdgcn_sched_barrier(0);

  int cur = 0;
  for (int kt = 0; kt < NK; kt += 2) {
    asm volatile("s_waitcnt vmcnt(2)" ::: "memory");
    __builtin_amdgcn_sched_barrier(0);
    __builtin_amdgcn_s_barrier();
    __builtin_amdgcn_sched_barrier(0);
    {
      const int nx1 = (cur == 2) ? 0 : cur + 1;
      const int nx2 = (nx1 == 2) ? 0 : nx1 + 1;
      if (kt + 1 < NK) LOADX(kt + 1, laB);
      __builtin_amdgcn_sched_barrier(0);
      if (kt + 2 < NK) STAGEW(nx2, kt + 2);
      __builtin_amdgcn_sched_barrier(0);
      COMPUTE(cur, laA);
      cur = nx1;
    }
    if (kt + 1 == NK - 1) asm volatile("s_waitcnt vmcnt(0)" ::: "memory");
    else                  asm volatile("s_waitcnt vmcnt(2)" ::: "memory");
    __builtin_amdgcn_sched_barrier(0);
    __builtin_amdgcn_s_barrier();
    __builtin_amdgcn_sched_barrier(0);
    {
      const int nx1 = (cur == 2) ? 0 : cur + 1;
      const int nx2 = (nx1 == 2) ? 0 : nx1 + 1;
      if (kt + 2 < NK) LOADX(kt + 2, laA);
      __builtin_amdgcn_sched_barrier(0);
      if (kt + 3 < NK) STAGEW(nx2, kt + 3);
      __builtin_amdgcn_sched_barrier(0);
      COMPUTE(cur, laB);
      cur = nx1;
    }
  }
#undef LOADX
#undef STAGEW
#undef COMPUTE

#pragma unroll
  for (int i = 0; i < 4; ++i) {
    const int nb = n0 + wnA + i * 16 + g * 4;
    const float4 b4 = *(const float4*)&bias[nb];
#pragma unroll
    for (int j = 0; j < 4; ++j) {
      const int m = m0 + wmB + j * 16 + fr;
      float4 v;
      v.x = acc[i][j][0] + b4.x;
      v.y = acc[i][j][1] + b4.y;
      v.z = acc[i][j][2] + b4.z;
      v.w = acc[i][j][3] + b4.w;
      *(float4*)&out[(size_t)m * 1024 + nb] = v;
    }
  }
}

// ---------------------------------------------------------------------------
// MFMA causal flash attention (unchanged from R6/R7).
// ---------------------------------------------------------------------------
__global__ __launch_bounds__(256) void attn_mfma(
    const unsigned short* __restrict__ qh, const unsigned short* __restrict__ kh,
    const unsigned short* __restrict__ vT, unsigned short* __restrict__ Ob) {
  __shared__ __align__(16) unsigned short Klds[2][64 * 64];
  __shared__ __align__(16) unsigned short Vlds[2][64 * 64];

  const int tid = threadIdx.x;
  const int lane = tid & 63;
  const int w = tid >> 6;
  const int bh = blockIdx.y;
  const int b = bh >> 4, h = bh & 15;
  const int q32 = lane & 31;
  const int hi = lane >> 5;

  const char* kbase = (const char*)(kh + (size_t)bh * 2048 * 64);
  const char* vbase = (const char*)(vT + (size_t)bh * 64 * 2048);

  const int lrow = lane >> 3;
  const int cb = (((lane & 7) ^ lrow) << 4);

  auto stage = [&](int buf, int t) {
    const int kv0 = t * 64;
#pragma unroll
    for (int j = 0; j < 2; ++j) {
      const int c = w * 2 + j;
      const int r = c * 8 + lrow;
      gload_lds16(kbase + (size_t)(kv0 + r) * 128 + cb,
                  (char*)Klds[buf] + c * 1024);
      gload_lds16(vbase + (size_t)r * 4096 + (size_t)kv0 * 2 + cb,
                  (char*)Vlds[buf] + c * 1024);
    }
  };

  for (int pass = 0; pass < 2; ++pass) {
    const int qt = pass == 0 ? (15 - (int)blockIdx.x) : (int)blockIdx.x;
    const int qb = qt * 128 + w * 32;
    const int nt = 2 * qt + 2;

    bf16x8 qf[4];
    {
      const unsigned short* qp = qh + ((size_t)bh * 2048 + qb + q32) * 64;
#pragma unroll
      for (int kk = 0; kk < 4; ++kk)
        qf[kk] = *(const bf16x8*)(qp + kk * 16 + hi * 8);
    }

    f32x16 acc_o[2] = {};
    float m_run = -INFINITY, l_run = 0.f;

    stage(0, 0);
    __syncthreads();

    int cur = 0;
    for (int t = 0; t < nt; ++t) {
      const int kv0 = t * 64;
      if (t + 1 < nt) stage(cur ^ 1, t + 1);

      if (kv0 < qb + 32) {
        const char* Kb = (const char*)Klds[cur];
        const char* Vb = (const char*)Vlds[cur];

        f32x16 sacc[2] = {};
        __builtin_amdgcn_s_setprio(1);
#pragma unroll
        for (int kk = 0; kk < 4; ++kk) {
          bf16x8 kf0 = *(const bf16x8*)(Kb + SWZ((q32) * 128 + kk * 32 + hi * 16));
          bf16x8 kf1 = *(const bf16x8*)(Kb + SWZ((32 + q32) * 128 + kk * 32 + hi * 16));
          sacc[0] = __builtin_amdgcn_mfma_f32_32x32x16_bf16(kf0, qf[kk], sacc[0], 0, 0, 0);
          sacc[1] = __builtin_amdgcn_mfma_f32_32x32x16_bf16(kf1, qf[kk], sacc[1], 0, 0, 0);
        }
        __builtin_amdgcn_s_setprio(0);

        if (kv0 + 64 > qb) {
          const int qa = qb + q32;
#pragma unroll
          for (int mkv = 0; mkv < 2; ++mkv)
#pragma unroll
            for (int r = 0; r < 16; ++r) {
              const int kva = kv0 + mkv * 32 + 4 * hi + (r & 3) + 8 * (r >> 2);
              if (kva > qa) sacc[mkv][r] = -INFINITY;
            }
        }

        float mx = -INFINITY;
#pragma unroll
        for (int mkv = 0; mkv < 2; ++mkv)
#pragma unroll
          for (int r = 0; r < 16; ++r) mx = fmaxf(mx, sacc[mkv][r]);
        mx = fmaxf(mx, __shfl_xor(mx, 32));
        if (!__all(mx <= m_run + 8.f)) {
          const float mnew = fmaxf(m_run, mx);
          const float al = exp2f(m_run - mnew);
          m_run = mnew;
          l_run *= al;
          acc_o[0] = acc_o[0] * al;
          acc_o[1] = acc_o[1] * al;
        }

        float ls = 0.f;
        unsigned W[2][8];
#pragma unroll
        for (int mkv = 0; mkv < 2; ++mkv)
#pragma unroll
          for (int s = 0; s < 8; ++s) {
            const float p0 = exp2f(sacc[mkv][2 * s] - m_run);
            const float p1 = exp2f(sacc[mkv][2 * s + 1] - m_run);
            ls += p0 + p1;
            W[mkv][s] = cvtpk_bf16(p0, p1);
          }
        ls += __shfl_xor(ls, 32);
        l_run += ls;

#pragma unroll
        for (int mkv = 0; mkv < 2; ++mkv) {
          pl32swap(W[mkv][0], W[mkv][2]);
          pl32swap(W[mkv][1], W[mkv][3]);
          pl32swap(W[mkv][4], W[mkv][6]);
          pl32swap(W[mkv][5], W[mkv][7]);
        }

        __builtin_amdgcn_s_setprio(1);
#pragma unroll
        for (int wg = 0; wg < 4; ++wg) {
          union { unsigned u[4]; bf16x8 v; } pk;
          pk.u[0] = W[wg >> 1][(wg & 1) * 4 + 0];
          pk.u[1] = W[wg >> 1][(wg & 1) * 4 + 1];
          pk.u[2] = W[wg >> 1][(wg & 1) * 4 + 2];
          pk.u[3] = W[wg >> 1][(wg & 1) * 4 + 3];
          bf16x8 vf0 = *(const bf16x8*)(Vb + SWZ((q32) * 128 + wg * 32 + hi * 16));
          bf16x8 vf1 = *(const bf16x8*)(Vb + SWZ((32 + q32) * 128 + wg * 32 + hi * 16));
          acc_o[0] = __builtin_amdgcn_mfma_f32_32x32x16_bf16(vf0, pk.v, acc_o[0], 0, 0, 0);
          acc_o[1] = __builtin_amdgcn_mfma_f32_32x32x16_bf16(vf1, pk.v, acc_o[1], 0, 0, 0);
        }
        __builtin_amdgcn_s_setprio(0);
      }

      __syncthreads();
      cur ^= 1;
    }

    {
      const float inv = 1.0f / l_run;
      const int qa = qb + q32;
      unsigned short* op = Ob + ((size_t)b * 2048 + qa) * 1024 + h * 64;
#pragma unroll
      for (int md = 0; md < 2; ++md)
#pragma unroll
        for (int rr = 0; rr < 4; ++rr) {
          uint2 u;
          u.x = cvtpk_bf16(acc_o[md][rr * 4 + 0] * inv, acc_o[md][rr * 4 + 1] * inv);
          u.y = cvtpk_bf16(acc_o[md][rr * 4 + 2] * inv, acc_o[md][rr * 4 + 3] * inv);
          *(uint2*)(op + md * 32 + rr * 8 + hi * 4) = u;
        }
    }
  }
}

extern "C" void kernel_launch(void* const* d_in, const int* in_sizes, int n_in,
                              void* d_out, int out_size, void* d_ws, size_t ws_size,
                              hipStream_t stream) {
  (void)in_sizes; (void)n_in; (void)out_size; (void)ws_size;
  const float* q = (const float*)d_in[0];
  const float* k = (const float*)d_in[1];
  const float* v = (const float*)d_in[2];
  const float* Wq = (const float*)d_in[3];
  const float* bq = (const float*)d_in[4];
  const float* Wk = (const float*)d_in[5];
  const float* bk = (const float*)d_in[6];
  const float* Wv = (const float*)d_in[7];
  const float* bv = (const float*)d_in[8];
  const float* Wo = (const float*)d_in[9];
  const float* bo = (const float*)d_in[10];
  float* out = (float*)d_out;

  const size_t SZ = (size_t)4 * 16 * 2048 * 64;   // 8,388,608 elements
  const size_t WSZ = (size_t)1024 * 1024;         // 1,048,576 elements
  unsigned short* qh = (unsigned short*)d_ws;
  unsigned short* kh = qh + SZ;
  unsigned short* vT = kh + SZ;    // V transposed: [bh][d][t]
  unsigned short* Ob = vT + SZ;    // attention output, [B][T][C] bf16
  unsigned short* Wqb = Ob + SZ;   // bf16 weights (Wq pre-scaled)
  unsigned short* Wkb = Wqb + WSZ;
  unsigned short* Wvb = Wkb + WSZ;
  unsigned short* Wob = Wvb + WSZ;

  dim3 g0(1024, 4), b0(256);
  cvt_w<<<g0, b0, 0, stream>>>(Wq, Wk, Wv, Wo, Wqb, Wkb, Wvb, Wob,
                               0.125f * 1.4426950408889634f);

  dim3 g1(64, 8, 3), b1(256);
  proj_gemm3<<<g1, b1, 0, stream>>>(q, k, v, Wqb, Wkb, Wvb, bq, bk, bv, qh, kh, vT);

  dim3 g2(8, 64), b2(256);
  attn_mfma<<<g2, b2, 0, stream>>>(qh, kh, vT, Ob);

  dim3 g3(64, 8), b3(256);
  out_gemm<<<g3, b3, 0, stream>>>(Ob, Wob, bo, out);
}

// Round 9
// 289.822 us; speedup vs baseline: 1.1617x; 1.1617x over previous
//
#include <hip/hip_runtime.h>
#include <hip/hip_bf16.h>

typedef __attribute__((ext_vector_type(8))) short bf16x8;
typedef __attribute__((ext_vector_type(4))) float f32x4;
typedef __attribute__((ext_vector_type(16))) float f32x16;

__device__ __forceinline__ unsigned short f2bf(float x) {
  union { float f; unsigned u; } v; v.f = x;
  unsigned r = v.u + 0x7fffu + ((v.u >> 16) & 1u);
  return (unsigned short)(r >> 16);
}

__device__ __forceinline__ unsigned cvtpk_bf16(float lo, float hi) {
  unsigned r;
  asm("v_cvt_pk_bf16_f32 %0, %1, %2" : "=v"(r) : "v"(lo), "v"(hi));
  return r;
}
__device__ __forceinline__ void pl32swap(unsigned &a, unsigned &b) {
  asm volatile("v_permlane32_swap_b32 %0, %1" : "+v"(a), "+v"(b));
}
__device__ __forceinline__ void gload_lds16(const void* g, void* l) {
  __builtin_amdgcn_global_load_lds((const __attribute__((address_space(1))) void*)g,
                                   (__attribute__((address_space(3))) void*)l, 16, 0, 0);
}

#define SWZ(x) ((x) ^ ((((x) >> 7) & 7) << 4))

// ---------------------------------------------------------------------------
// Weight fp32 -> bf16 pre-convert (Wq scaled by s0).
// ---------------------------------------------------------------------------
__global__ __launch_bounds__(256) void cvt_w(
    const float* __restrict__ W0, const float* __restrict__ W1,
    const float* __restrict__ W2, const float* __restrict__ W3,
    unsigned short* __restrict__ o0, unsigned short* __restrict__ o1,
    unsigned short* __restrict__ o2, unsigned short* __restrict__ o3,
    float s0) {
  const int z = blockIdx.y;
  const float* W = (z == 0) ? W0 : (z == 1) ? W1 : (z == 2) ? W2 : W3;
  unsigned short* o = (z == 0) ? o0 : (z == 1) ? o1 : (z == 2) ? o2 : o3;
  const float s = (z == 0) ? s0 : 1.0f;
  const int i = blockIdx.x * 256 + threadIdx.x;
  const float4 x = ((const float4*)W)[i];
  uint2 u;
  u.x = cvtpk_bf16(x.x * s, x.y * s);
  u.y = cvtpk_bf16(x.z * s, x.w * s);
  ((uint2*)o)[i] = u;
}

// ===========================================================================
// GEMM structure (R7-proven ring-3 + counted vmcnt), upsized to 256x128 tile,
// 8 waves (512 threads). Per wave: 64x64 C sub-tile, 8 ds_read_b128 -> 16
// MFMA per K-step; 128 MFMA per barrier (2x R7). LDS = ring-3 x (16KB A +
// 8KB B) = 72KB -> 2 blocks/CU (16 waves).
// LDS tile layout ([R rows][32 k] bf16): pair p=r>>1, 16B chunk c(0..3),
//   gc=((r&1)*4+c)^(p&7), byte addr p*128+gc*16 -- conflict-free (R6: 0).
// Ring hazard audit: buffer written at substep s is next read at s+1 (A) /
//   staged 2 ahead (B); all reuse separated by >=2 barriers.
// ===========================================================================

// ---------------------------------------------------------------------------
// Merged Q/K/V projection GEMM. z: 0=Q (Wq pre-scaled), 1=K, 2=V(transposed).
// A fp32 reg-staged (la0/la1 ping-pong, cvt_pk, swizzled b128 writes);
// B bf16 via global_load_lds. Per-substep VMEM issue = 4 A-loads + 1 B-gload
// = 5 -> steady wait vmcnt(5) drains substep s-2 (incl. B for this step).
// ---------------------------------------------------------------------------
__global__ __launch_bounds__(512, 4) void proj_gemm3(
    const float* __restrict__ A0, const float* __restrict__ A1, const float* __restrict__ A2,
    const unsigned short* __restrict__ W0b, const unsigned short* __restrict__ W1b,
    const unsigned short* __restrict__ W2b,
    const float* __restrict__ b0, const float* __restrict__ b1, const float* __restrict__ b2,
    unsigned short* __restrict__ o0, unsigned short* __restrict__ o1,
    unsigned short* __restrict__ o2) {
  const int K = 1024;
  const int NK = 32;
  __shared__ __align__(16) unsigned short As[3][8192];  // 256 x 32 bf16
  __shared__ __align__(16) unsigned short Bs[3][4096];  // 128 x 32 bf16
  const int z = blockIdx.z;
  const float* A = (z == 0) ? A0 : (z == 1) ? A1 : A2;
  const unsigned short* Wb = (z == 0) ? W0b : (z == 1) ? W1b : W2b;
  const float* bias = (z == 0) ? b0 : (z == 1) ? b1 : b2;
  unsigned short* out = (z == 0) ? o0 : (z == 1) ? o1 : o2;
  const float bscale = (z == 0) ? 0.125f * 1.4426950408889634f : 1.0f;
  const int vtrans = (z == 2);

  const int tid = threadIdx.x;
  const int row0 = blockIdx.x * 256;
  const int col0 = blockIdx.y * 128;
  const int lane = tid & 63;
  const int w = tid >> 6;
  const int wm = (w >> 1) * 64;   // m offset in 256
  const int wn = (w & 1) * 64;    // n offset in 128
  const int fr = lane & 15;
  const int g = lane >> 4;
  const int frh = fr >> 1;
  const int gcf = ((fr & 1) * 4 + g) ^ frh;
  const int aoff = wm * 64 + frh * 128 + gcf * 16;
  const int boff = wn * 64 + frh * 128 + gcf * 16;

  // A staging: thread covers rows ar, ar+128; fp32 cols (tid&3)*8..+7
  const int ar = tid >> 2;
  const int acq = tid & 3;
  const float* asrc0 = &A[(size_t)(row0 + ar) * K + acq * 8];
  const float* asrc1 = asrc0 + (size_t)128 * K;
  const int awr = (ar >> 1) * 128 + ((((ar & 1) * 4 + acq) ^ ((ar >> 1) & 7)) * 16);

  // B staging via gload_lds: wave w -> chunk L = w*64+lane (512 chunks total)
  const unsigned short* bsrc;
  int bldo;
  {
    const int L = w * 64 + lane;
    const int pp = L >> 3, gc = L & 7;
    const int e = gc ^ (pp & 7);
    const int r = pp * 2 + (e >> 2), c = e & 3;
    bsrc = Wb + (size_t)(col0 + r) * K + c * 8;
    bldo = w * 1024;  // wave-uniform byte base (HW adds lane*16)
  }

  f32x4 acc[4][4] = {};
  float4 la0[4], la1[4];

#define LOADA(kt, LA)                                        \
  {                                                          \
    const float* s0_ = asrc0 + (kt) * 32;                    \
    const float* s1_ = asrc1 + (kt) * 32;                    \
    LA[0] = *(const float4*)s0_; LA[1] = *(const float4*)(s0_ + 4); \
    LA[2] = *(const float4*)s1_; LA[3] = *(const float4*)(s1_ + 4); \
  }
#define STOREA(buf, LA)                                               \
  {                                                                   \
    uint4 u0_, u1_;                                                   \
    u0_.x = cvtpk_bf16(LA[0].x, LA[0].y); u0_.y = cvtpk_bf16(LA[0].z, LA[0].w); \
    u0_.z = cvtpk_bf16(LA[1].x, LA[1].y); u0_.w = cvtpk_bf16(LA[1].z, LA[1].w); \
    u1_.x = cvtpk_bf16(LA[2].x, LA[2].y); u1_.y = cvtpk_bf16(LA[2].z, LA[2].w); \
    u1_.z = cvtpk_bf16(LA[3].x, LA[3].y); u1_.w = cvtpk_bf16(LA[3].z, LA[3].w); \
    char* base_ = (char*)As[buf];                                     \
    *(uint4*)(base_ + awr) = u0_;                                     \
    *(uint4*)(base_ + awr + 8192) = u1_;  /* row+128 -> pair+64 */    \
  }
#define STAGEB(buf, kt)                                               \
  { gload_lds16(bsrc + (kt) * 32, (char*)Bs[buf] + bldo); }
#define COMPUTE(cb)                                                   \
  {                                                                   \
    const char* Ab_ = (const char*)As[cb];                            \
    const char* Bb_ = (const char*)Bs[cb];                            \
    bf16x8 af[4], bfv[4];                                             \
    _Pragma("unroll")                                                 \
    for (int i = 0; i < 4; ++i) {                                     \
      af[i] = *(const bf16x8*)(Ab_ + aoff + i * 1024);                \
      bfv[i] = *(const bf16x8*)(Bb_ + boff + i * 1024);               \
    }                                                                 \
    _Pragma("unroll")                                                 \
    for (int i = 0; i < 4; ++i)                                       \
      _Pragma("unroll")                                               \
      for (int j = 0; j < 4; ++j)                                     \
        acc[i][j] = __builtin_amdgcn_mfma_f32_16x16x32_bf16(af[i], bfv[j], acc[i][j], 0, 0, 0); \
  }

  // prologue: B0,B1 in flight; A0 staged to LDS, A1 in regs
  STAGEB(0, 0); STAGEB(1, 1);
  LOADA(0, la0); LOADA(1, la1);
  STOREA(0, la0);
  asm volatile("s_waitcnt lgkmcnt(0)" ::: "memory");

  int cur = 0;
  for (int kt = 0; kt < NK; kt += 2) {
    // ---------- even sub-step: consume buf[cur]=kt ----------
    if (kt == 0) asm volatile("s_waitcnt vmcnt(0)" ::: "memory");
    else         asm volatile("s_waitcnt vmcnt(5)" ::: "memory");
    __builtin_amdgcn_sched_barrier(0);
    __builtin_amdgcn_s_barrier();
    __builtin_amdgcn_sched_barrier(0);
    {
      const int nx1 = (cur == 2) ? 0 : cur + 1;
      const int nx2 = (nx1 == 2) ? 0 : nx1 + 1;
      if (kt + 2 < NK) { LOADA(kt + 2, la0); STAGEB(nx2, kt + 2); }
      __builtin_amdgcn_sched_barrier(0);
      COMPUTE(cur);
      STOREA(nx1, la1);  // A(kt+1) -> next buffer
      asm volatile("s_waitcnt lgkmcnt(0)" ::: "memory");
      cur = nx1;
    }
    // ---------- odd sub-step: consume buf[cur]=kt+1 ----------
    if (kt + 1 == NK - 1) asm volatile("s_waitcnt vmcnt(0)" ::: "memory");
    else                  asm volatile("s_waitcnt vmcnt(5)" ::: "memory");
    __builtin_amdgcn_sched_barrier(0);
    __builtin_amdgcn_s_barrier();
    __builtin_amdgcn_sched_barrier(0);
    {
      const int nx1 = (cur == 2) ? 0 : cur + 1;
      const int nx2 = (nx1 == 2) ? 0 : nx1 + 1;
      if (kt + 3 < NK) { LOADA(kt + 3, la1); STAGEB(nx2, kt + 3); }
      __builtin_amdgcn_sched_barrier(0);
      COMPUTE(cur);
      if (kt + 2 < NK) {
        STOREA(nx1, la0);  // A(kt+2) -> next buffer
        asm volatile("s_waitcnt lgkmcnt(0)" ::: "memory");
      }
      cur = nx1;
    }
  }
#undef LOADA
#undef STOREA
#undef STAGEB
#undef COMPUTE

#pragma unroll
  for (int j = 0; j < 4; ++j) {
    const int n = col0 + wn + j * 16 + fr;
    const float bv = bias[n] * bscale;
    const int h = n >> 6, d = n & 63;
#pragma unroll
    for (int i = 0; i < 4; ++i) {
      const int mrow = row0 + wm + i * 16 + g * 4;
      const int b = mrow >> 11, t0 = mrow & 2047;
      if (vtrans) {
        uint2 u;
        u.x = cvtpk_bf16(acc[i][j][0] + bv, acc[i][j][1] + bv);
        u.y = cvtpk_bf16(acc[i][j][2] + bv, acc[i][j][3] + bv);
        *(uint2*)(&out[(((size_t)b * 16 + h) * 64 + d) * 2048 + t0]) = u;
      } else {
#pragma unroll
        for (int r = 0; r < 4; ++r)
          out[(((size_t)b * 16 + h) * 2048 + (t0 + r)) * 64 + d] = f2bf(acc[i][j][r] + bv);
      }
    }
  }
}

// ---------------------------------------------------------------------------
// Output projection: both operands bf16, pure gload_lds, ring-3 counted
// vmcnt. 256x128 tile, 8 waves. Per-substep issue = 2 A + 1 B gload = 3.
// ---------------------------------------------------------------------------
__global__ __launch_bounds__(512, 4) void out_gemm(
    const unsigned short* __restrict__ A, const unsigned short* __restrict__ Wb,
    const float* __restrict__ bias, float* __restrict__ out) {
  const int K = 1024;
  const int NK = 32;
  __shared__ __align__(16) unsigned short As[3][8192];
  __shared__ __align__(16) unsigned short Bs[3][4096];
  const int tid = threadIdx.x;
  const int row0 = blockIdx.x * 256;
  const int col0 = blockIdx.y * 128;
  const int lane = tid & 63;
  const int w = tid >> 6;
  const int wm = (w >> 1) * 64;
  const int wn = (w & 1) * 64;
  const int fr = lane & 15;
  const int g = lane >> 4;
  const int frh = fr >> 1;
  const int gcf = ((fr & 1) * 4 + g) ^ frh;
  const int aoff = wm * 64 + frh * 128 + gcf * 16;
  const int boff = wn * 64 + frh * 128 + gcf * 16;

  // A: 1024 chunks -> 2 gloads/thread; B: 512 chunks -> 1 gload/thread
  const unsigned short* asrc[2];
  int aldo[2];
#pragma unroll
  for (int j = 0; j < 2; ++j) {
    const int L = (w * 2 + j) * 64 + lane;
    const int pp = L >> 3, gc = L & 7;
    const int e = gc ^ (pp & 7);
    const int r = pp * 2 + (e >> 2), c = e & 3;
    asrc[j] = A + (size_t)(row0 + r) * K + c * 8;
    aldo[j] = (w * 2 + j) * 1024;
  }
  const unsigned short* bsrc;
  int bldo;
  {
    const int L = w * 64 + lane;
    const int pp = L >> 3, gc = L & 7;
    const int e = gc ^ (pp & 7);
    const int r = pp * 2 + (e >> 2), c = e & 3;
    bsrc = Wb + (size_t)(col0 + r) * K + c * 8;
    bldo = w * 1024;
  }

  f32x4 acc[4][4] = {};

  auto stage = [&](int buf, int kt) {
    gload_lds16(asrc[0] + kt * 32, (char*)As[buf] + aldo[0]);
    gload_lds16(asrc[1] + kt * 32, (char*)As[buf] + aldo[1]);
    gload_lds16(bsrc + kt * 32, (char*)Bs[buf] + bldo);
  };

  stage(0, 0); stage(1, 1);
  int cur = 0;
  for (int kt = 0; kt < NK; ++kt) {
    if (kt == 0 || kt == NK - 1) asm volatile("s_waitcnt vmcnt(0)" ::: "memory");
    else                         asm volatile("s_waitcnt vmcnt(3)" ::: "memory");
    __builtin_amdgcn_sched_barrier(0);
    __builtin_amdgcn_s_barrier();
    __builtin_amdgcn_sched_barrier(0);
    const int nx1 = (cur == 2) ? 0 : cur + 1;
    const int nx2 = (nx1 == 2) ? 0 : nx1 + 1;
    if (kt + 2 < NK) stage(nx2, kt + 2);
    __builtin_amdgcn_sched_barrier(0);
    const char* Ab = (const char*)As[cur];
    const char* Bb = (const char*)Bs[cur];
    bf16x8 af[4], bfv[4];
#pragma unroll
    for (int i = 0; i < 4; ++i) {
      af[i] = *(const bf16x8*)(Ab + aoff + i * 1024);
      bfv[i] = *(const bf16x8*)(Bb + boff + i * 1024);
    }
#pragma unroll
    for (int i = 0; i < 4; ++i)
#pragma unroll
      for (int j = 0; j < 4; ++j)
        acc[i][j] = __builtin_amdgcn_mfma_f32_16x16x32_bf16(af[i], bfv[j], acc[i][j], 0, 0, 0);
    cur = nx1;
  }

#pragma unroll
  for (int j = 0; j < 4; ++j) {
    const int n = col0 + wn + j * 16 + fr;
    const float bv = bias[n];
#pragma unroll
    for (int i = 0; i < 4; ++i) {
      const int mrow = row0 + wm + i * 16 + g * 4;
#pragma unroll
      for (int r = 0; r < 4; ++r)
        out[(size_t)(mrow + r) * 1024 + n] = acc[i][j][r] + bv;
    }
  }
}

// ---------------------------------------------------------------------------
// MFMA causal flash attention (unchanged from R6/R7).
// ---------------------------------------------------------------------------
__global__ __launch_bounds__(256) void attn_mfma(
    const unsigned short* __restrict__ qh, const unsigned short* __restrict__ kh,
    const unsigned short* __restrict__ vT, unsigned short* __restrict__ Ob) {
  __shared__ __align__(16) unsigned short Klds[2][64 * 64];
  __shared__ __align__(16) unsigned short Vlds[2][64 * 64];

  const int tid = threadIdx.x;
  const int lane = tid & 63;
  const int w = tid >> 6;
  const int bh = blockIdx.y;
  const int b = bh >> 4, h = bh & 15;
  const int q32 = lane & 31;
  const int hi = lane >> 5;

  const char* kbase = (const char*)(kh + (size_t)bh * 2048 * 64);
  const char* vbase = (const char*)(vT + (size_t)bh * 64 * 2048);

  const int lrow = lane >> 3;
  const int cb = (((lane & 7) ^ lrow) << 4);

  auto stage = [&](int buf, int t) {
    const int kv0 = t * 64;
#pragma unroll
    for (int j = 0; j < 2; ++j) {
      const int c = w * 2 + j;
      const int r = c * 8 + lrow;
      gload_lds16(kbase + (size_t)(kv0 + r) * 128 + cb,
                  (char*)Klds[buf] + c * 1024);
      gload_lds16(vbase + (size_t)r * 4096 + (size_t)kv0 * 2 + cb,
                  (char*)Vlds[buf] + c * 1024);
    }
  };

  for (int pass = 0; pass < 2; ++pass) {
    const int qt = pass == 0 ? (15 - (int)blockIdx.x) : (int)blockIdx.x;
    const int qb = qt * 128 + w * 32;
    const int nt = 2 * qt + 2;

    bf16x8 qf[4];
    {
      const unsigned short* qp = qh + ((size_t)bh * 2048 + qb + q32) * 64;
#pragma unroll
      for (int kk = 0; kk < 4; ++kk)
        qf[kk] = *(const bf16x8*)(qp + kk * 16 + hi * 8);
    }

    f32x16 acc_o[2] = {};
    float m_run = -INFINITY, l_run = 0.f;

    stage(0, 0);
    __syncthreads();

    int cur = 0;
    for (int t = 0; t < nt; ++t) {
      const int kv0 = t * 64;
      if (t + 1 < nt) stage(cur ^ 1, t + 1);

      if (kv0 < qb + 32) {
        const char* Kb = (const char*)Klds[cur];
        const char* Vb = (const char*)Vlds[cur];

        f32x16 sacc[2] = {};
        __builtin_amdgcn_s_setprio(1);
#pragma unroll
        for (int kk = 0; kk < 4; ++kk) {
          bf16x8 kf0 = *(const bf16x8*)(Kb + SWZ((q32) * 128 + kk * 32 + hi * 16));
          bf16x8 kf1 = *(const bf16x8*)(Kb + SWZ((32 + q32) * 128 + kk * 32 + hi * 16));
          sacc[0] = __builtin_amdgcn_mfma_f32_32x32x16_bf16(kf0, qf[kk], sacc[0], 0, 0, 0);
          sacc[1] = __builtin_amdgcn_mfma_f32_32x32x16_bf16(kf1, qf[kk], sacc[1], 0, 0, 0);
        }
        __builtin_amdgcn_s_setprio(0);

        if (kv0 + 64 > qb) {
          const int qa = qb + q32;
#pragma unroll
          for (int mkv = 0; mkv < 2; ++mkv)
#pragma unroll
            for (int r = 0; r < 16; ++r) {
              const int kva = kv0 + mkv * 32 + 4 * hi + (r & 3) + 8 * (r >> 2);
              if (kva > qa) sacc[mkv][r] = -INFINITY;
            }
        }

        float mx = -INFINITY;
#pragma unroll
        for (int mkv = 0; mkv < 2; ++mkv)
#pragma unroll
          for (int r = 0; r < 16; ++r) mx = fmaxf(mx, sacc[mkv][r]);
        mx = fmaxf(mx, __shfl_xor(mx, 32));
        if (!__all(mx <= m_run + 8.f)) {
          const float mnew = fmaxf(m_run, mx);
          const float al = exp2f(m_run - mnew);
          m_run = mnew;
          l_run *= al;
          acc_o[0] = acc_o[0] * al;
          acc_o[1] = acc_o[1] * al;
        }

        float ls = 0.f;
        unsigned W[2][8];
#pragma unroll
        for (int mkv = 0; mkv < 2; ++mkv)
#pragma unroll
          for (int s = 0; s < 8; ++s) {
            const float p0 = exp2f(sacc[mkv][2 * s] - m_run);
            const float p1 = exp2f(sacc[mkv][2 * s + 1] - m_run);
            ls += p0 + p1;
            W[mkv][s] = cvtpk_bf16(p0, p1);
          }
        ls += __shfl_xor(ls, 32);
        l_run += ls;

#pragma unroll
        for (int mkv = 0; mkv < 2; ++mkv) {
          pl32swap(W[mkv][0], W[mkv][2]);
          pl32swap(W[mkv][1], W[mkv][3]);
          pl32swap(W[mkv][4], W[mkv][6]);
          pl32swap(W[mkv][5], W[mkv][7]);
        }

        __builtin_amdgcn_s_setprio(1);
#pragma unroll
        for (int wg = 0; wg < 4; ++wg) {
          union { unsigned u[4]; bf16x8 v; } pk;
          pk.u[0] = W[wg >> 1][(wg & 1) * 4 + 0];
          pk.u[1] = W[wg >> 1][(wg & 1) * 4 + 1];
          pk.u[2] = W[wg >> 1][(wg & 1) * 4 + 2];
          pk.u[3] = W[wg >> 1][(wg & 1) * 4 + 3];
          bf16x8 vf0 = *(const bf16x8*)(Vb + SWZ((q32) * 128 + wg * 32 + hi * 16));
          bf16x8 vf1 = *(const bf16x8*)(Vb + SWZ((32 + q32) * 128 + wg * 32 + hi * 16));
          acc_o[0] = __builtin_amdgcn_mfma_f32_32x32x16_bf16(vf0, pk.v, acc_o[0], 0, 0, 0);
          acc_o[1] = __builtin_amdgcn_mfma_f32_32x32x16_bf16(vf1, pk.v, acc_o[1], 0, 0, 0);
        }
        __builtin_amdgcn_s_setprio(0);
      }

      __syncthreads();
      cur ^= 1;
    }

    {
      const float inv = 1.0f / l_run;
      const int qa = qb + q32;
      unsigned short* op = Ob + ((size_t)b * 2048 + qa) * 1024 + h * 64;
#pragma unroll
      for (int md = 0; md < 2; ++md)
#pragma unroll
        for (int rr = 0; rr < 4; ++rr) {
          uint2 u;
          u.x = cvtpk_bf16(acc_o[md][rr * 4 + 0] * inv, acc_o[md][rr * 4 + 1] * inv);
          u.y = cvtpk_bf16(acc_o[md][rr * 4 + 2] * inv, acc_o[md][rr * 4 + 3] * inv);
          *(uint2*)(op + md * 32 + rr * 8 + hi * 4) = u;
        }
    }
  }
}

extern "C" void kernel_launch(void* const* d_in, const int* in_sizes, int n_in,
                              void* d_out, int out_size, void* d_ws, size_t ws_size,
                              hipStream_t stream) {
  (void)in_sizes; (void)n_in; (void)out_size; (void)ws_size;
  const float* q = (const float*)d_in[0];
  const float* k = (const float*)d_in[1];
  const float* v = (const float*)d_in[2];
  const float* Wq = (const float*)d_in[3];
  const float* bq = (const float*)d_in[4];
  const float* Wk = (const float*)d_in[5];
  const float* bk = (const float*)d_in[6];
  const float* Wv = (const float*)d_in[7];
  const float* bv = (const float*)d_in[8];
  const float* Wo = (const float*)d_in[9];
  const float* bo = (const float*)d_in[10];
  float* out = (float*)d_out;

  const size_t SZ = (size_t)4 * 16 * 2048 * 64;   // 8,388,608 elements
  const size_t WSZ = (size_t)1024 * 1024;         // 1,048,576 elements
  unsigned short* qh = (unsigned short*)d_ws;
  unsigned short* kh = qh + SZ;
  unsigned short* vT = kh + SZ;    // V transposed: [bh][d][t]
  unsigned short* Ob = vT + SZ;    // attention output, [B][T][C] bf16
  unsigned short* Wqb = Ob + SZ;   // bf16 weights (Wq pre-scaled)
  unsigned short* Wkb = Wqb + WSZ;
  unsigned short* Wvb = Wkb + WSZ;
  unsigned short* Wob = Wvb + WSZ;

  dim3 g0(1024, 4), b0(256);
  cvt_w<<<g0, b0, 0, stream>>>(Wq, Wk, Wv, Wo, Wqb, Wkb, Wvb, Wob,
                               0.125f * 1.4426950408889634f);

  dim3 g1(32, 8, 3), b1(512);
  proj_gemm3<<<g1, b1, 0, stream>>>(q, k, v, Wqb, Wkb, Wvb, bq, bk, bv, qh, kh, vT);

  dim3 g2(8, 64), b2(256);
  attn_mfma<<<g2, b2, 0, stream>>>(qh, kh, vT, Ob);

  dim3 g3(32, 8), b3(512);
  out_gemm<<<g3, b3, 0, stream>>>(Ob, Wob, bo, out);
}

// Round 10
// 210.905 us; speedup vs baseline: 1.5964x; 1.3742x over previous
//
#include <hip/hip_runtime.h>
#include <hip/hip_bf16.h>

typedef __attribute__((ext_vector_type(8))) short bf16x8;
typedef __attribute__((ext_vector_type(4))) float f32x4;
typedef __attribute__((ext_vector_type(16))) float f32x16;

__device__ __forceinline__ unsigned short f2bf(float x) {
  union { float f; unsigned u; } v; v.f = x;
  unsigned r = v.u + 0x7fffu + ((v.u >> 16) & 1u);
  return (unsigned short)(r >> 16);
}

__device__ __forceinline__ unsigned cvtpk_bf16(float lo, float hi) {
  unsigned r;
  asm("v_cvt_pk_bf16_f32 %0, %1, %2" : "=v"(r) : "v"(lo), "v"(hi));
  return r;
}
__device__ __forceinline__ void pl32swap(unsigned &a, unsigned &b) {
  asm volatile("v_permlane32_swap_b32 %0, %1" : "+v"(a), "+v"(b));
}
__device__ __forceinline__ void gload_lds16(const void* g, void* l) {
  __builtin_amdgcn_global_load_lds((const __attribute__((address_space(1))) void*)g,
                                   (__attribute__((address_space(3))) void*)l, 16, 0, 0);
}

#define SWZ(x) ((x) ^ ((((x) >> 7) & 7) << 4))

// ---------------------------------------------------------------------------
// Weight fp32 -> bf16 pre-convert (Wq scaled by s0).
// ---------------------------------------------------------------------------
__global__ __launch_bounds__(256) void cvt_w(
    const float* __restrict__ W0, const float* __restrict__ W1,
    const float* __restrict__ W2, const float* __restrict__ W3,
    unsigned short* __restrict__ o0, unsigned short* __restrict__ o1,
    unsigned short* __restrict__ o2, unsigned short* __restrict__ o3,
    float s0) {
  const int z = blockIdx.y;
  const float* W = (z == 0) ? W0 : (z == 1) ? W1 : (z == 2) ? W2 : W3;
  unsigned short* o = (z == 0) ? o0 : (z == 1) ? o1 : (z == 2) ? o2 : o3;
  const float s = (z == 0) ? s0 : 1.0f;
  const int i = blockIdx.x * 256 + threadIdx.x;
  const float4 x = ((const float4*)W)[i];
  uint2 u;
  u.x = cvtpk_bf16(x.x * s, x.y * s);
  u.y = cvtpk_bf16(x.z * s, x.w * s);
  ((uint2*)o)[i] = u;
}

// ---------------------------------------------------------------------------
// Activation fp32 -> bf16 pre-convert (q, k, v).
// ---------------------------------------------------------------------------
__global__ __launch_bounds__(256) void cvt_x(
    const float* __restrict__ q, const float* __restrict__ k,
    const float* __restrict__ v,
    unsigned short* __restrict__ oq, unsigned short* __restrict__ ok,
    unsigned short* __restrict__ ov) {
  const int z = blockIdx.y;
  const float* X = (z == 0) ? q : (z == 1) ? k : v;
  unsigned short* o = (z == 0) ? oq : (z == 1) ? ok : ov;
  const int i = blockIdx.x * 256 + threadIdx.x;
  const float4 x = ((const float4*)X)[i];
  uint2 u;
  u.x = cvtpk_bf16(x.x, x.y);
  u.y = cvtpk_bf16(x.z, x.w);
  ((uint2*)o)[i] = u;
}

// ===========================================================================
// Pure-gload bf16 GEMM, 128x128 tile, BK=64 (NK=16), 4 waves, 2-phase dbuf.
// Both operands staged via global_load_lds (inverse-swizzled per-lane global
// source, linear LDS dest). Per 16KB buffer: two 8KB halves (k 0..31, 32..63),
// each [128 rows][32 k] with pair p=r>>1, chunk c, gc=((r&1)*4+c)^(p&7),
// byte addr p*128+gc*16 -- conflict-free (R6-verified: SQ_LDS_BANK_CONFLICT=0).
// Loop per step: STAGE(next) issued FIRST (T3 minimum), COMPUTE (2 halves x
// (8 ds_read_b128 + 16 MFMA) with setprio), one __syncthreads.
// LDS = 2x16KB x 2 = 64KB -> 2 blocks/CU for cross-block drain overlap.
// ===========================================================================

// ---------------------------------------------------------------------------
// Merged Q/K/V projection GEMM (A bf16 from cvt_x).
// z: 0=Q (Wq pre-scaled), 1=K, 2=V(transposed out).
// ---------------------------------------------------------------------------
__global__ __launch_bounds__(256) void proj_gemm3(
    const unsigned short* __restrict__ X0, const unsigned short* __restrict__ X1,
    const unsigned short* __restrict__ X2,
    const unsigned short* __restrict__ W0b, const unsigned short* __restrict__ W1b,
    const unsigned short* __restrict__ W2b,
    const float* __restrict__ b0, const float* __restrict__ b1, const float* __restrict__ b2,
    unsigned short* __restrict__ o0, unsigned short* __restrict__ o1,
    unsigned short* __restrict__ o2) {
  const int K = 1024;
  const int NK = 16;
  __shared__ __align__(16) unsigned short As[2][8192];  // 2 halves x 128x32
  __shared__ __align__(16) unsigned short Bs[2][8192];
  const int z = blockIdx.z;
  const unsigned short* A = (z == 0) ? X0 : (z == 1) ? X1 : X2;
  const unsigned short* Wb = (z == 0) ? W0b : (z == 1) ? W1b : W2b;
  const float* bias = (z == 0) ? b0 : (z == 1) ? b1 : b2;
  unsigned short* out = (z == 0) ? o0 : (z == 1) ? o1 : o2;
  const float bscale = (z == 0) ? 0.125f * 1.4426950408889634f : 1.0f;
  const int vtrans = (z == 2);

  const int tid = threadIdx.x;
  const int row0 = blockIdx.x * 128;
  const int col0 = blockIdx.y * 128;
  const int lane = tid & 63;
  const int w = tid >> 6;
  const int wm = (w >> 1) * 64, wn = (w & 1) * 64;
  const int fr = lane & 15;
  const int g = lane >> 4;
  const int frh = fr >> 1;
  const int gcf = ((fr & 1) * 4 + g) ^ frh;
  const int aoff = wm * 64 + frh * 128 + gcf * 16;  // within an 8KB half
  const int boff = wn * 64 + frh * 128 + gcf * 16;

  // gload sources: per half, chunk L=(w*2+j)*64+lane; (r,c) independent of half
  const unsigned short* asrc[2];
  const unsigned short* bsrc[2];
  int ldo[2];
#pragma unroll
  for (int j = 0; j < 2; ++j) {
    const int L = (w * 2 + j) * 64 + lane;
    const int pp = L >> 3, gc = L & 7;
    const int e = gc ^ (pp & 7);
    const int r = pp * 2 + (e >> 2), c = e & 3;
    asrc[j] = A + (size_t)(row0 + r) * K + c * 8;
    bsrc[j] = Wb + (size_t)(col0 + r) * K + c * 8;
    ldo[j] = (w * 2 + j) * 1024;  // wave-uniform byte base (HW adds lane*16)
  }

  f32x4 acc[4][4] = {};

  auto stage = [&](int buf, int kt) {
#pragma unroll
    for (int h = 0; h < 2; ++h)
#pragma unroll
      for (int j = 0; j < 2; ++j) {
        gload_lds16(asrc[j] + kt * 64 + h * 32, (char*)As[buf] + h * 8192 + ldo[j]);
        gload_lds16(bsrc[j] + kt * 64 + h * 32, (char*)Bs[buf] + h * 8192 + ldo[j]);
      }
  };

  stage(0, 0);
  __syncthreads();
  for (int kt = 0; kt < NK; ++kt) {
    const int buf = kt & 1;
    if (kt + 1 < NK) stage(buf ^ 1, kt + 1);
#pragma unroll
    for (int h = 0; h < 2; ++h) {
      const char* Ab = (const char*)As[buf] + h * 8192;
      const char* Bb = (const char*)Bs[buf] + h * 8192;
      bf16x8 af[4], bfv[4];
#pragma unroll
      for (int i = 0; i < 4; ++i) {
        af[i] = *(const bf16x8*)(Ab + aoff + i * 1024);
        bfv[i] = *(const bf16x8*)(Bb + boff + i * 1024);
      }
      __builtin_amdgcn_s_setprio(1);
#pragma unroll
      for (int i = 0; i < 4; ++i)
#pragma unroll
        for (int j = 0; j < 4; ++j)
          acc[i][j] = __builtin_amdgcn_mfma_f32_16x16x32_bf16(af[i], bfv[j], acc[i][j], 0, 0, 0);
      __builtin_amdgcn_s_setprio(0);
    }
    __syncthreads();
  }

#pragma unroll
  for (int j = 0; j < 4; ++j) {
    const int n = col0 + wn + j * 16 + fr;
    const float bv = bias[n] * bscale;
    const int h = n >> 6, d = n & 63;
#pragma unroll
    for (int i = 0; i < 4; ++i) {
      const int mrow = row0 + wm + i * 16 + g * 4;
      const int b = mrow >> 11, t0 = mrow & 2047;
      if (vtrans) {
        uint2 u;
        u.x = cvtpk_bf16(acc[i][j][0] + bv, acc[i][j][1] + bv);
        u.y = cvtpk_bf16(acc[i][j][2] + bv, acc[i][j][3] + bv);
        *(uint2*)(&out[(((size_t)b * 16 + h) * 64 + d) * 2048 + t0]) = u;
      } else {
#pragma unroll
        for (int r = 0; r < 4; ++r)
          out[(((size_t)b * 16 + h) * 2048 + (t0 + r)) * 64 + d] = f2bf(acc[i][j][r] + bv);
      }
    }
  }
}

// ---------------------------------------------------------------------------
// Output projection: same structure, fp32 output + bias.
// ---------------------------------------------------------------------------
__global__ __launch_bounds__(256) void out_gemm(
    const unsigned short* __restrict__ A, const unsigned short* __restrict__ Wb,
    const float* __restrict__ bias, float* __restrict__ out) {
  const int K = 1024;
  const int NK = 16;
  __shared__ __align__(16) unsigned short As[2][8192];
  __shared__ __align__(16) unsigned short Bs[2][8192];
  const int tid = threadIdx.x;
  const int row0 = blockIdx.x * 128;
  const int col0 = blockIdx.y * 128;
  const int lane = tid & 63;
  const int w = tid >> 6;
  const int wm = (w >> 1) * 64, wn = (w & 1) * 64;
  const int fr = lane & 15;
  const int g = lane >> 4;
  const int frh = fr >> 1;
  const int gcf = ((fr & 1) * 4 + g) ^ frh;
  const int aoff = wm * 64 + frh * 128 + gcf * 16;
  const int boff = wn * 64 + frh * 128 + gcf * 16;

  const unsigned short* asrc[2];
  const unsigned short* bsrc[2];
  int ldo[2];
#pragma unroll
  for (int j = 0; j < 2; ++j) {
    const int L = (w * 2 + j) * 64 + lane;
    const int pp = L >> 3, gc = L & 7;
    const int e = gc ^ (pp & 7);
    const int r = pp * 2 + (e >> 2), c = e & 3;
    asrc[j] = A + (size_t)(row0 + r) * K + c * 8;
    bsrc[j] = Wb + (size_t)(col0 + r) * K + c * 8;
    ldo[j] = (w * 2 + j) * 1024;
  }

  f32x4 acc[4][4] = {};

  auto stage = [&](int buf, int kt) {
#pragma unroll
    for (int h = 0; h < 2; ++h)
#pragma unroll
      for (int j = 0; j < 2; ++j) {
        gload_lds16(asrc[j] + kt * 64 + h * 32, (char*)As[buf] + h * 8192 + ldo[j]);
        gload_lds16(bsrc[j] + kt * 64 + h * 32, (char*)Bs[buf] + h * 8192 + ldo[j]);
      }
  };

  stage(0, 0);
  __syncthreads();
  for (int kt = 0; kt < NK; ++kt) {
    const int buf = kt & 1;
    if (kt + 1 < NK) stage(buf ^ 1, kt + 1);
#pragma unroll
    for (int h = 0; h < 2; ++h) {
      const char* Ab = (const char*)As[buf] + h * 8192;
      const char* Bb = (const char*)Bs[buf] + h * 8192;
      bf16x8 af[4], bfv[4];
#pragma unroll
      for (int i = 0; i < 4; ++i) {
        af[i] = *(const bf16x8*)(Ab + aoff + i * 1024);
        bfv[i] = *(const bf16x8*)(Bb + boff + i * 1024);
      }
      __builtin_amdgcn_s_setprio(1);
#pragma unroll
      for (int i = 0; i < 4; ++i)
#pragma unroll
        for (int j = 0; j < 4; ++j)
          acc[i][j] = __builtin_amdgcn_mfma_f32_16x16x32_bf16(af[i], bfv[j], acc[i][j], 0, 0, 0);
      __builtin_amdgcn_s_setprio(0);
    }
    __syncthreads();
  }

#pragma unroll
  for (int j = 0; j < 4; ++j) {
    const int n = col0 + wn + j * 16 + fr;
    const float bv = bias[n];
#pragma unroll
    for (int i = 0; i < 4; ++i) {
      const int mrow = row0 + wm + i * 16 + g * 4;
#pragma unroll
      for (int r = 0; r < 4; ++r)
        out[(size_t)(mrow + r) * 1024 + n] = acc[i][j][r] + bv;
    }
  }
}

// ---------------------------------------------------------------------------
// MFMA causal flash attention (unchanged from R6/R7).
// ---------------------------------------------------------------------------
__global__ __launch_bounds__(256) void attn_mfma(
    const unsigned short* __restrict__ qh, const unsigned short* __restrict__ kh,
    const unsigned short* __restrict__ vT, unsigned short* __restrict__ Ob) {
  __shared__ __align__(16) unsigned short Klds[2][64 * 64];
  __shared__ __align__(16) unsigned short Vlds[2][64 * 64];

  const int tid = threadIdx.x;
  const int lane = tid & 63;
  const int w = tid >> 6;
  const int bh = blockIdx.y;
  const int b = bh >> 4, h = bh & 15;
  const int q32 = lane & 31;
  const int hi = lane >> 5;

  const char* kbase = (const char*)(kh + (size_t)bh * 2048 * 64);
  const char* vbase = (const char*)(vT + (size_t)bh * 64 * 2048);

  const int lrow = lane >> 3;
  const int cb = (((lane & 7) ^ lrow) << 4);

  auto stage = [&](int buf, int t) {
    const int kv0 = t * 64;
#pragma unroll
    for (int j = 0; j < 2; ++j) {
      const int c = w * 2 + j;
      const int r = c * 8 + lrow;
      gload_lds16(kbase + (size_t)(kv0 + r) * 128 + cb,
                  (char*)Klds[buf] + c * 1024);
      gload_lds16(vbase + (size_t)r * 4096 + (size_t)kv0 * 2 + cb,
                  (char*)Vlds[buf] + c * 1024);
    }
  };

  for (int pass = 0; pass < 2; ++pass) {
    const int qt = pass == 0 ? (15 - (int)blockIdx.x) : (int)blockIdx.x;
    const int qb = qt * 128 + w * 32;
    const int nt = 2 * qt + 2;

    bf16x8 qf[4];
    {
      const unsigned short* qp = qh + ((size_t)bh * 2048 + qb + q32) * 64;
#pragma unroll
      for (int kk = 0; kk < 4; ++kk)
        qf[kk] = *(const bf16x8*)(qp + kk * 16 + hi * 8);
    }

    f32x16 acc_o[2] = {};
    float m_run = -INFINITY, l_run = 0.f;

    stage(0, 0);
    __syncthreads();

    int cur = 0;
    for (int t = 0; t < nt; ++t) {
      const int kv0 = t * 64;
      if (t + 1 < nt) stage(cur ^ 1, t + 1);

      if (kv0 < qb + 32) {
        const char* Kb = (const char*)Klds[cur];
        const char* Vb = (const char*)Vlds[cur];

        f32x16 sacc[2] = {};
        __builtin_amdgcn_s_setprio(1);
#pragma unroll
        for (int kk = 0; kk < 4; ++kk) {
          bf16x8 kf0 = *(const bf16x8*)(Kb + SWZ((q32) * 128 + kk * 32 + hi * 16));
          bf16x8 kf1 = *(const bf16x8*)(Kb + SWZ((32 + q32) * 128 + kk * 32 + hi * 16));
          sacc[0] = __builtin_amdgcn_mfma_f32_32x32x16_bf16(kf0, qf[kk], sacc[0], 0, 0, 0);
          sacc[1] = __builtin_amdgcn_mfma_f32_32x32x16_bf16(kf1, qf[kk], sacc[1], 0, 0, 0);
        }
        __builtin_amdgcn_s_setprio(0);

        if (kv0 + 64 > qb) {
          const int qa = qb + q32;
#pragma unroll
          for (int mkv = 0; mkv < 2; ++mkv)
#pragma unroll
            for (int r = 0; r < 16; ++r) {
              const int kva = kv0 + mkv * 32 + 4 * hi + (r & 3) + 8 * (r >> 2);
              if (kva > qa) sacc[mkv][r] = -INFINITY;
            }
        }

        float mx = -INFINITY;
#pragma unroll
        for (int mkv = 0; mkv < 2; ++mkv)
#pragma unroll
          for (int r = 0; r < 16; ++r) mx = fmaxf(mx, sacc[mkv][r]);
        mx = fmaxf(mx, __shfl_xor(mx, 32));
        if (!__all(mx <= m_run + 8.f)) {
          const float mnew = fmaxf(m_run, mx);
          const float al = exp2f(m_run - mnew);
          m_run = mnew;
          l_run *= al;
          acc_o[0] = acc_o[0] * al;
          acc_o[1] = acc_o[1] * al;
        }

        float ls = 0.f;
        unsigned W[2][8];
#pragma unroll
        for (int mkv = 0; mkv < 2; ++mkv)
#pragma unroll
          for (int s = 0; s < 8; ++s) {
            const float p0 = exp2f(sacc[mkv][2 * s] - m_run);
            const float p1 = exp2f(sacc[mkv][2 * s + 1] - m_run);
            ls += p0 + p1;
            W[mkv][s] = cvtpk_bf16(p0, p1);
          }
        ls += __shfl_xor(ls, 32);
        l_run += ls;

#pragma unroll
        for (int mkv = 0; mkv < 2; ++mkv) {
          pl32swap(W[mkv][0], W[mkv][2]);
          pl32swap(W[mkv][1], W[mkv][3]);
          pl32swap(W[mkv][4], W[mkv][6]);
          pl32swap(W[mkv][5], W[mkv][7]);
        }

        __builtin_amdgcn_s_setprio(1);
#pragma unroll
        for (int wg = 0; wg < 4; ++wg) {
          union { unsigned u[4]; bf16x8 v; } pk;
          pk.u[0] = W[wg >> 1][(wg & 1) * 4 + 0];
          pk.u[1] = W[wg >> 1][(wg & 1) * 4 + 1];
          pk.u[2] = W[wg >> 1][(wg & 1) * 4 + 2];
          pk.u[3] = W[wg >> 1][(wg & 1) * 4 + 3];
          bf16x8 vf0 = *(const bf16x8*)(Vb + SWZ((q32) * 128 + wg * 32 + hi * 16));
          bf16x8 vf1 = *(const bf16x8*)(Vb + SWZ((32 + q32) * 128 + wg * 32 + hi * 16));
          acc_o[0] = __builtin_amdgcn_mfma_f32_32x32x16_bf16(vf0, pk.v, acc_o[0], 0, 0, 0);
          acc_o[1] = __builtin_amdgcn_mfma_f32_32x32x16_bf16(vf1, pk.v, acc_o[1], 0, 0, 0);
        }
        __builtin_amdgcn_s_setprio(0);
      }

      __syncthreads();
      cur ^= 1;
    }

    {
      const float inv = 1.0f / l_run;
      const int qa = qb + q32;
      unsigned short* op = Ob + ((size_t)b * 2048 + qa) * 1024 + h * 64;
#pragma unroll
      for (int md = 0; md < 2; ++md)
#pragma unroll
        for (int rr = 0; rr < 4; ++rr) {
          uint2 u;
          u.x = cvtpk_bf16(acc_o[md][rr * 4 + 0] * inv, acc_o[md][rr * 4 + 1] * inv);
          u.y = cvtpk_bf16(acc_o[md][rr * 4 + 2] * inv, acc_o[md][rr * 4 + 3] * inv);
          *(uint2*)(op + md * 32 + rr * 8 + hi * 4) = u;
        }
    }
  }
}

extern "C" void kernel_launch(void* const* d_in, const int* in_sizes, int n_in,
                              void* d_out, int out_size, void* d_ws, size_t ws_size,
                              hipStream_t stream) {
  (void)in_sizes; (void)n_in; (void)out_size; (void)ws_size;
  const float* q = (const float*)d_in[0];
  const float* k = (const float*)d_in[1];
  const float* v = (const float*)d_in[2];
  const float* Wq = (const float*)d_in[3];
  const float* bq = (const float*)d_in[4];
  const float* Wk = (const float*)d_in[5];
  const float* bk = (const float*)d_in[6];
  const float* Wv = (const float*)d_in[7];
  const float* bv = (const float*)d_in[8];
  const float* Wo = (const float*)d_in[9];
  const float* bo = (const float*)d_in[10];
  float* out = (float*)d_out;

  const size_t SZ = (size_t)4 * 16 * 2048 * 64;   // 8,388,608 elements
  const size_t WSZ = (size_t)1024 * 1024;         // 1,048,576 elements
  unsigned short* qx = (unsigned short*)d_ws;     // bf16 activations [m][k]
  unsigned short* kx = qx + SZ;
  unsigned short* vx = kx + SZ;
  unsigned short* qh = vx + SZ;                   // [b][h][t][d]
  unsigned short* kh = qh + SZ;
  unsigned short* vT = kh + SZ;                   // [b][h][d][t]
  unsigned short* Wqb = vT + SZ;                  // bf16 weights (Wq pre-scaled)
  unsigned short* Wkb = Wqb + WSZ;
  unsigned short* Wvb = Wkb + WSZ;
  unsigned short* Wob = Wvb + WSZ;
  unsigned short* Ob = qx;  // alias: qx dead after proj_gemm3, attn writes here

  dim3 g0(1024, 4), b0(256);
  cvt_w<<<g0, b0, 0, stream>>>(Wq, Wk, Wv, Wo, Wqb, Wkb, Wvb, Wob,
                               0.125f * 1.4426950408889634f);
  dim3 gx(8192, 3), bx(256);
  cvt_x<<<gx, bx, 0, stream>>>(q, k, v, qx, kx, vx);

  dim3 g1(64, 8, 3), b1(256);
  proj_gemm3<<<g1, b1, 0, stream>>>(qx, kx, vx, Wqb, Wkb, Wvb, bq, bk, bv,
                                    qh, kh, vT);

  dim3 g2(8, 64), b2(256);
  attn_mfma<<<g2, b2, 0, stream>>>(qh, kh, vT, Ob);

  dim3 g3(64, 8), b3(256);
  out_gemm<<<g3, b3, 0, stream>>>(Ob, Wob, bo, out);
}